// Round 12
// baseline (204.357 us; speedup 1.0000x reference)
//
#include <hip/hip_runtime.h>
#include <hip/hip_fp16.h>

// Problem constants (match reference.py)
#define NN 50000        // nodes
#define EE 1600000      // edges before self-loops
#define TOT (EE + NN)   // edges after self-loops
#define INC 128         // in channels
#define HC 128          // H*C out channels
#define NEG_SLOPE 0.2f

// binning (64-node ranges, r9-proven)
#define EPB 4096                        // edges per bin block
#define NB1 ((TOT + EPB - 1) / EPB)     // 403 bin blocks
#define RNG2 64                         // nodes per dst-range
#define NR2 ((NN + RNG2 - 1) / RNG2)    // 782 ranges
#define CAPR2 2624                      // edges/range cap (mean 2110, sigma 46; +11 sigma)
#define PADC (CAPR2 + 4 * RNG2)         // padded LDS-CSR capacity (4 slack/node)
#define PROJB ((NN + 63) / 64)          // 782 proj blocks

// fp16 store: x held as __half; aggr consumes it via v_fma_mix_f32.
__device__ __forceinline__ unsigned short f2h(float f) {
    __half h = __float2half(f);
    return __half_as_ushort(h);
}

// pack two f32 -> u32 of 2x f16 (builtin returns __fp16 vec2 — r8 lesson)
__device__ __forceinline__ unsigned int packp(float a, float b) {
    typedef __fp16 h2 __attribute__((ext_vector_type(2)));
    union { h2 h; unsigned int u; } cv;
    cv.h = __builtin_amdgcn_cvt_pkrtz(a, b);
    return cv.u;
}

// ---------------------------------------------------------------------------
// proj body (r6/r9-proven VALU version): x = h @ W stored fp16 + fused
// attention a_s/a_d. (r11's MFMA rewrite measured neutral-to-negative;
// fused1 is not proj-FLOP-bound — reverted.)
#define LOADW(dst, kk)                                                        \
    _Pragma("unroll") for (int q = 0; q < 4; q++) {                           \
        float4 wv4 = *reinterpret_cast<const float4*>(&W[(size_t)((kk) + q) * HC + j2 * 4]); \
        dst[q][0] = wv4.x; dst[q][1] = wv4.y; dst[q][2] = wv4.z; dst[q][3] = wv4.w; \
    }

#define FMAS(wv, kk)                                                          \
    _Pragma("unroll") for (int r8 = 0; r8 < 8; r8++) {                        \
        const float* hr = hs + (rg * 8 + r8) * INC + (kk);                    \
        float4 hv = *reinterpret_cast<const float4*>(hr);                     \
        _Pragma("unroll") for (int c = 0; c < 4; c++)                         \
            acc[r8][c] += hv.x * wv[0][c] + hv.y * wv[1][c]                   \
                        + hv.z * wv[2][c] + hv.w * wv[3][c];                  \
    }

__device__ __forceinline__ void proj_body(
        char* smem, int pb,
        const float* __restrict__ h, const float* __restrict__ W,
        const float* __restrict__ att_src, const float* __restrict__ att_dst,
        unsigned short* __restrict__ x_h,
        float* __restrict__ a_s, float* __restrict__ a_d) {
    float* hs = (float*)smem;            // [64][INC] = 32 KB
    const int t = threadIdx.x;
    const int row0 = pb * 64;

    for (int q = t; q < 64 * 32; q += 256) {
        int rr = q >> 5;
        int c4 = (q & 31) << 2;
        int gr = row0 + rr;
        float4 v = (gr < NN) ? *reinterpret_cast<const float4*>(&h[(size_t)gr * INC + c4])
                             : make_float4(0.f, 0.f, 0.f, 0.f);
        *reinterpret_cast<float4*>(&hs[rr * INC + c4]) = v;
    }
    __syncthreads();

    const int j2 = t & 31;   // cols j2*4 .. j2*4+3
    const int rg = t >> 5;
    float acc[8][4];
#pragma unroll
    for (int r8 = 0; r8 < 8; r8++)
#pragma unroll
        for (int c = 0; c < 4; c++) acc[r8][c] = 0.f;

    float wA[4][4], wB[4][4];
    LOADW(wA, 0)
    for (int k = 0; k < INC; k += 8) {
        LOADW(wB, k + 4)
        FMAS(wA, k)
        if (k + 8 < INC) { LOADW(wA, k + 8) }
        FMAS(wB, k + 4)
    }

#pragma unroll
    for (int r8 = 0; r8 < 8; r8++) {
        int gr = row0 + rg * 8 + r8;
        if (gr < NN) {
            ushort4 sv;
            sv.x = f2h(acc[r8][0]);
            sv.y = f2h(acc[r8][1]);
            sv.z = f2h(acc[r8][2]);
            sv.w = f2h(acc[r8][3]);
            *reinterpret_cast<ushort4*>(&x_h[(size_t)gr * HC + j2 * 4]) = sv;
        }
    }

    // fused attention epilogue: lanes j2=0..15 hold head0 cols, 16..31 head1
    const int lane = t & 63;
    const int hidx = j2 >> 4;
    const float4 avs = *reinterpret_cast<const float4*>(&att_src[j2 * 4]);
    const float4 avd = *reinterpret_cast<const float4*>(&att_dst[j2 * 4]);
#pragma unroll
    for (int r8 = 0; r8 < 8; r8++) {
        float ps = acc[r8][0] * avs.x + acc[r8][1] * avs.y
                 + acc[r8][2] * avs.z + acc[r8][3] * avs.w;
        float pd = acc[r8][0] * avd.x + acc[r8][1] * avd.y
                 + acc[r8][2] * avd.z + acc[r8][3] * avd.w;
#pragma unroll
        for (int o = 1; o < 16; o <<= 1) {
            ps += __shfl_xor(ps, o);
            pd += __shfl_xor(pd, o);
        }
        int gr = row0 + rg * 8 + r8;
        if ((lane & 15) == 0 && gr < NN) {
            a_s[gr * 2 + hidx] = ps;
            a_d[gr * 2 + hidx] = pd;
        }
    }
}

// ---------------------------------------------------------------------------
// bin body (r9-proven): LDS counters + scan + LDS staging -> coalesced gbin.
// key (64-node ranges): (range10<<22) | ((dst&63)<<16) | src16
__device__ __forceinline__ void bin_body(
        char* smem, int b,
        const int* __restrict__ ei,
        unsigned int* __restrict__ gbin, unsigned short* __restrict__ bofs) {
    int* cnt = (int*)smem;                               // NR2
    int* ofs = cnt + NR2;                                // NR2+1
    int* cur = ofs + NR2 + 1;                            // NR2
    int* wsum = cur + NR2;                               // 4
    unsigned int* lbuf = (unsigned int*)(wsum + 4);      // EPB (16 KB) -> ~25.2 KB total
    const int t = threadIdx.x;

    for (int i = t; i < NR2; i += 256) cnt[i] = 0;
    __syncthreads();

    unsigned int pk[16];
    bool vd[16];
#pragma unroll
    for (int q = 0; q < 16; q++) {
        int i = b * EPB + q * 256 + t;
        vd[q] = (i < TOT);
        int s, d;
        if (i < EE)       { s = ei[i]; d = ei[EE + i]; }
        else if (i < TOT) { s = d = i - EE; }
        else              { s = d = 0; }
        pk[q] = ((unsigned int)(d >> 6) << 22) |
                ((unsigned int)(d & 63) << 16) | (unsigned int)s;
        if (vd[q]) atomicAdd(&cnt[pk[q] >> 22], 1);     // LDS atomic
    }
    __syncthreads();

    // exclusive scan cnt[0..NR2) -> ofs[0..NR2]; cur = copy (4 elems/thread)
    {
        int i0 = 4 * t;
        int v0 = (i0     < NR2) ? cnt[i0]     : 0;
        int v1 = (i0 + 1 < NR2) ? cnt[i0 + 1] : 0;
        int v2 = (i0 + 2 < NR2) ? cnt[i0 + 2] : 0;
        int v3 = (i0 + 3 < NR2) ? cnt[i0 + 3] : 0;
        int ps = v0 + v1 + v2 + v3;
        int sc = ps;
        int lane = t & 63, wid = t >> 6;
#pragma unroll
        for (int o = 1; o < 64; o <<= 1) {
            int u = __shfl_up(sc, o);
            if (lane >= o) sc += u;
        }
        if (lane == 63) wsum[wid] = sc;
        __syncthreads();
        int woff = 0;
        for (int ww = 0; ww < wid; ww++) woff += wsum[ww];
        int run = woff + sc - ps;
        if (i0     <= NR2) ofs[i0]     = run; if (i0     < NR2) cur[i0]     = run; run += v0;
        if (i0 + 1 <= NR2) ofs[i0 + 1] = run; if (i0 + 1 < NR2) cur[i0 + 1] = run; run += v1;
        if (i0 + 2 <= NR2) ofs[i0 + 2] = run; if (i0 + 2 < NR2) cur[i0 + 2] = run; run += v2;
        if (i0 + 3 <= NR2) ofs[i0 + 3] = run; if (i0 + 3 < NR2) cur[i0 + 3] = run;
    }
    __syncthreads();

#pragma unroll
    for (int q = 0; q < 16; q++) {
        if (vd[q]) {
            int pos = atomicAdd(&cur[pk[q] >> 22], 1);  // LDS atomic
            lbuf[pos] = pk[q];
        }
    }
    __syncthreads();

#pragma unroll
    for (int q = 0; q < 16; q++)
        gbin[(size_t)b * EPB + q * 256 + t] = lbuf[q * 256 + t];
    for (int i = t; i <= NR2; i += 256)
        bofs[(size_t)b * (NR2 + 1) + i] = (unsigned short)ofs[i];
}

// ---------------------------------------------------------------------------
// K1: fat kernel — blocks [0,NB1) bin, blocks [NB1,NB1+PROJB) proj+att.
__global__ __launch_bounds__(256) void gat_fused1(
        const float* __restrict__ h, const float* __restrict__ W,
        const float* __restrict__ att_src, const float* __restrict__ att_dst,
        const int* __restrict__ ei,
        unsigned int* __restrict__ gbin, unsigned short* __restrict__ bofs,
        unsigned short* __restrict__ x_h,
        float* __restrict__ a_s, float* __restrict__ a_d) {
    __shared__ __align__(16) char smem[64 * INC * 4];   // 32 KB union
    if (blockIdx.x < NB1)
        bin_body(smem, blockIdx.x, ei, gbin, bofs);
    else
        proj_body(smem, blockIdx.x - NB1, h, W, att_src, att_dst, x_h, a_s, a_d);
}

// ---------------------------------------------------------------------------
// K2: MERGED build+aggregate (r9-proven). Single change vs r9: phase-4
// channel loop deepened from ILP-4 to ILP-8 (8 independent x-row loads in
// flight per wave) to probe whether any of ragg's 71us is latency-
// underutilization rather than pure fabric throughput.
#define ACCUM(u32v, aL, aH)                                                   \
    asm("v_fma_mix_f32 %0, %1, %2, %0 op_sel_hi:[0,1,0]"                      \
        : "+v"(aL) : "v"(wk), "v"(u32v));                                     \
    asm("v_fma_mix_f32 %0, %1, %2, %0 op_sel:[0,1,0] op_sel_hi:[0,1,0]"       \
        : "+v"(aH) : "v"(wk), "v"(u32v));

__global__ __launch_bounds__(512) void gat_ragg(
        const unsigned int* __restrict__ gbin,
        const unsigned short* __restrict__ bofs,
        const uint4* __restrict__ x16,           // fp16 row = 16 x uint4
        const float2* __restrict__ a_s2, const float2* __restrict__ a_d2,
        const float4* __restrict__ bias4, float4* __restrict__ out4) {
    __shared__ int sbase[512];                 // segment-start scan (403 used)
    __shared__ int segofs[NB1];                // segment offset within its bin
    __shared__ unsigned short esrc[CAPR2];
    __shared__ unsigned char  edst[CAPR2];
    __shared__ unsigned int   pvh[CAPR2];      // fp16x2 p per edge
    __shared__ unsigned short csrc[PADC];      // ordered src per node-window
    __shared__ unsigned int   cpv[PADC];       // ordered fp16x2 p
    __shared__ int deg[RNG2];
    __shared__ int ofsP[RNG2];                 // padded window starts (+4/node)
    __shared__ int cur[RNG2];
    __shared__ int wsum[8];
    __shared__ int tot_sh;

    const int t = threadIdx.x;
    const int r = blockIdx.x;
    const int lane = t & 63, wid = t >> 6;

    if (t < RNG2) { deg[t] = 0; cur[t] = 0; }

    // phase 0: segment lengths (1/thread) -> 8-wave scan -> sbase, tot
    int c = 0;
    if (t < NB1) {
        int o0 = (int)bofs[(size_t)t * (NR2 + 1) + r];
        int o1 = (int)bofs[(size_t)t * (NR2 + 1) + r + 1];
        c = o1 - o0;
        segofs[t] = o0;
    }
    int sc = c;
#pragma unroll
    for (int o = 1; o < 64; o <<= 1) {
        int u = __shfl_up(sc, o);
        if (lane >= o) sc += u;
    }
    if (lane == 63) wsum[wid] = sc;
    __syncthreads();
    int woff = 0;
    for (int ww = 0; ww < wid; ww++) woff += wsum[ww];
    int excl = woff + sc - c;
    sbase[t] = excl;
    if (t == 511) tot_sh = excl + c;
    __syncthreads();
    const int tot = min(tot_sh, CAPR2);

    // phase 1: flat gather gbin -> LDS (binary search sbase), p compute,
    // degree count. All loads independent across e.
    const float2* __restrict__ adr = a_d2 + (size_t)r * RNG2;
    for (int e = t; e < tot; e += 512) {
        int lo = 0, hi = NB1 - 1;              // largest j with sbase[j] <= e
        while (lo < hi) {
            int mid = (lo + hi + 1) >> 1;
            if (sbase[mid] <= e) lo = mid; else hi = mid - 1;
        }
        unsigned int v = gbin[(size_t)lo * EPB + segofs[lo] + (e - sbase[lo])];
        int s  = (int)(v & 0xFFFFu);
        int dl = (int)((v >> 16) & 63u);
        esrc[e] = (unsigned short)s;
        edst[e] = (unsigned char)dl;
        float2 as = a_s2[s];
        float2 ad = adr[dl];                   // edge exists -> node valid
        float e0 = as.x + ad.x; e0 = (e0 > 0.f) ? e0 : NEG_SLOPE * e0;
        float e1 = as.y + ad.y; e1 = (e1 > 0.f) ? e1 : NEG_SLOPE * e1;
        pvh[e] = packp(__expf(e0), __expf(e1));
        atomicAdd(&deg[dl], 1);                // LDS atomic
    }
    __syncthreads();

    // phase 2: padded exclusive scan deg -> ofsP (wave 0 only; RNG2 == 64)
    if (t < RNG2) {
        int v = deg[t];
        int s2 = v;
#pragma unroll
        for (int o = 1; o < 64; o <<= 1) {
            int u = __shfl_up(s2, o);
            if (lane >= o) s2 += u;
        }
        ofsP[t] = (s2 - v) + 4 * t;            // +4 slack slots per node
    }
    __syncthreads();

    // phase 3: scatter (src, p) into node windows + zero the 4-pad
    for (int e = t; e < tot; e += 512) {
        int dl = edst[e];
        int slot = ofsP[dl] + atomicAdd(&cur[dl], 1);   // LDS atomic
        csrc[slot] = esrc[e];
        cpv[slot]  = pvh[e];
    }
    if (t < RNG2 * 4) {
        int j = t >> 2, q = t & 3;
        int slot = ofsP[j] + deg[j] + q;
        csrc[slot] = 0;
        cpv[slot] = 0;
    }
    __syncthreads();

    // phase 4: aggregate — wave w handles nodes w, w+8, ... (8 nodes/wave)
    const int sub = lane >> 4;           // edge index within 4-edge group
    const int cl  = lane & 15;           // channel oct
    const int hd  = cl >> 3;             // head
    const int hsh = hd << 4;             // shift to select head's half
    for (int jl = wid; jl < RNG2; jl += 8) {
        int n = r * RNG2 + jl;
        if (n >= NN) continue;
        const int dj = deg[jl];
        const int w0 = ofsP[jl];

        // denominators from stored p
        float d0 = 0.f, d1 = 0.f;
        for (int jj = lane; jj < dj; jj += 64) {
            unsigned int ph = cpv[w0 + jj];
            d0 += __half2float(__ushort_as_half((unsigned short)ph));
            d1 += __half2float(__ushort_as_half((unsigned short)(ph >> 16)));
        }
#pragma unroll
        for (int off = 32; off; off >>= 1) {
            d0 += __shfl_xor(d0, off);
            d1 += __shfl_xor(d1, off);
        }

        // channel loop: 4-edge groups; ILP-8 -> ILP-4 -> scalar remainder
        float a0=0.f,a1=0.f,a2=0.f,a3=0.f,a4=0.f,a5=0.f,a6=0.f,a7=0.f;
        const int ng = (dj + 3) >> 2;
        int g = 0;
        for (; g + 8 <= ng; g += 8) {
#pragma unroll
            for (int k = 0; k < 8; k++) {
                int e = 4 * (g + k) + sub;
                int s = (int)csrc[w0 + e];
                unsigned int ph = cpv[w0 + e];
                float wk = __half2float(__ushort_as_half((unsigned short)(ph >> hsh)));
                uint4 u = x16[(size_t)s * 16 + cl];
                ACCUM(u.x, a0, a1)
                ACCUM(u.y, a2, a3)
                ACCUM(u.z, a4, a5)
                ACCUM(u.w, a6, a7)
            }
        }
        for (; g + 4 <= ng; g += 4) {
#pragma unroll
            for (int k = 0; k < 4; k++) {
                int e = 4 * (g + k) + sub;
                int s = (int)csrc[w0 + e];
                unsigned int ph = cpv[w0 + e];
                float wk = __half2float(__ushort_as_half((unsigned short)(ph >> hsh)));
                uint4 u = x16[(size_t)s * 16 + cl];
                ACCUM(u.x, a0, a1)
                ACCUM(u.y, a2, a3)
                ACCUM(u.z, a4, a5)
                ACCUM(u.w, a6, a7)
            }
        }
        for (; g < ng; g++) {
            int e = 4 * g + sub;
            int s = (int)csrc[w0 + e];
            unsigned int ph = cpv[w0 + e];
            float wk = __half2float(__ushort_as_half((unsigned short)(ph >> hsh)));
            uint4 u = x16[(size_t)s * 16 + cl];
            ACCUM(u.x, a0, a1)
            ACCUM(u.y, a2, a3)
            ACCUM(u.z, a4, a5)
            ACCUM(u.w, a6, a7)
        }
#define MRG(a) a += __shfl_xor(a, 16); a += __shfl_xor(a, 32);
        MRG(a0) MRG(a1) MRG(a2) MRG(a3) MRG(a4) MRG(a5) MRG(a6) MRG(a7)
#undef MRG

        // epilogue spread over 32 lanes (r6-proven)
        if (lane < 32) {
            const int hf = lane >> 4;
            const float invd = 1.0f / (hd ? d1 : d0);
            float4 bb = bias4[cl * 2 + hf];
            float v0 = (hf ? a4 : a0) * invd + bb.x;
            float v1 = (hf ? a5 : a1) * invd + bb.y;
            float v2 = (hf ? a6 : a2) * invd + bb.z;
            float v3 = (hf ? a7 : a3) * invd + bb.w;
            v0 = (v0 > 0.f) ? v0 : __expf(v0) - 1.0f;
            v1 = (v1 > 0.f) ? v1 : __expf(v1) - 1.0f;
            v2 = (v2 > 0.f) ? v2 : __expf(v2) - 1.0f;
            v3 = (v3 > 0.f) ? v3 : __expf(v3) - 1.0f;
            out4[(size_t)n * 32 + cl * 2 + hf] = make_float4(v0, v1, v2, v3);
        }
    }
}

// ---------------------------------------------------------------------------
static inline size_t align256(size_t v) { return (v + 255) & ~(size_t)255; }

extern "C" void kernel_launch(void* const* d_in, const int* in_sizes, int n_in,
                              void* d_out, int out_size, void* d_ws, size_t ws_size,
                              hipStream_t stream) {
    const float* h_node  = (const float*)d_in[0];
    const int*   ei      = (const int*)d_in[1];
    const float* W       = (const float*)d_in[2];
    const float* att_src = (const float*)d_in[3];
    const float* att_dst = (const float*)d_in[4];
    const float* bias    = (const float*)d_in[5];
    float* out = (float*)d_out;

    // workspace layout (~21 MB)
    char* base = (char*)d_ws;
    size_t off = 0;
    unsigned short* x_h = (unsigned short*)(base + off);
    off = align256(off + (size_t)NN * HC * 2);
    float* a_s = (float*)(base + off);      off = align256(off + (size_t)NN * 2 * 4);
    float* a_d = (float*)(base + off);      off = align256(off + (size_t)NN * 2 * 4);
    unsigned int* gbin = (unsigned int*)(base + off);
    off = align256(off + (size_t)NB1 * EPB * 4);
    unsigned short* bofs = (unsigned short*)(base + off);
    off = align256(off + (size_t)NB1 * (NR2 + 1) * 2);
    (void)ws_size;

    gat_fused1<<<NB1 + PROJB, 256, 0, stream>>>(h_node, W, att_src, att_dst, ei,
                                                gbin, bofs, x_h, a_s, a_d);
    gat_ragg<<<NR2, 512, 0, stream>>>(gbin, bofs, (const uint4*)x_h,
                                      (const float2*)a_s, (const float2*)a_d,
                                      (const float4*)bias, (float4*)out);
}

// Round 13
// 186.702 us; speedup vs baseline: 1.0946x; 1.0946x over previous
//
#include <hip/hip_runtime.h>
#include <hip/hip_fp16.h>

// Problem constants (match reference.py)
#define NN 50000        // nodes
#define EE 1600000      // edges before self-loops
#define TOT (EE + NN)   // edges after self-loops
#define INC 128         // in channels
#define HC 128          // H*C out channels
#define NEG_SLOPE 0.2f

// binning (64-node ranges, r9-proven)
#define EPB 4096                        // edges per bin block
#define NB1 ((TOT + EPB - 1) / EPB)     // 403 bin blocks
#define RNG2 64                         // nodes per dst-range
#define NR2 ((NN + RNG2 - 1) / RNG2)    // 782 ranges
#define CAPR2 2624                      // edges/range cap (mean 2110, sigma 46; +11 sigma)
#define PADC (CAPR2 + 4 * RNG2)         // padded LDS-CSR capacity (4 slack/node)
#define PROJB ((NN + 63) / 64)          // 782 proj blocks

// fp16 store: x held as __half; aggr consumes it via v_fma_mix_f32.
__device__ __forceinline__ unsigned short f2h(float f) {
    __half h = __float2half(f);
    return __half_as_ushort(h);
}

// pack two f32 -> u32 of 2x f16 (builtin returns __fp16 vec2 — r8 lesson)
__device__ __forceinline__ unsigned int packp(float a, float b) {
    typedef __fp16 h2 __attribute__((ext_vector_type(2)));
    union { h2 h; unsigned int u; } cv;
    cv.h = __builtin_amdgcn_cvt_pkrtz(a, b);
    return cv.u;
}

// ---------------------------------------------------------------------------
// proj body (r6/r9-proven VALU version): x = h @ W stored fp16 + fused
// attention a_s/a_d.
#define LOADW(dst, kk)                                                        \
    _Pragma("unroll") for (int q = 0; q < 4; q++) {                           \
        float4 wv4 = *reinterpret_cast<const float4*>(&W[(size_t)((kk) + q) * HC + j2 * 4]); \
        dst[q][0] = wv4.x; dst[q][1] = wv4.y; dst[q][2] = wv4.z; dst[q][3] = wv4.w; \
    }

#define FMAS(wv, kk)                                                          \
    _Pragma("unroll") for (int r8 = 0; r8 < 8; r8++) {                        \
        const float* hr = hs + (rg * 8 + r8) * INC + (kk);                    \
        float4 hv = *reinterpret_cast<const float4*>(hr);                     \
        _Pragma("unroll") for (int c = 0; c < 4; c++)                         \
            acc[r8][c] += hv.x * wv[0][c] + hv.y * wv[1][c]                   \
                        + hv.z * wv[2][c] + hv.w * wv[3][c];                  \
    }

__device__ __forceinline__ void proj_body(
        char* smem, int pb,
        const float* __restrict__ h, const float* __restrict__ W,
        const float* __restrict__ att_src, const float* __restrict__ att_dst,
        unsigned short* __restrict__ x_h,
        float* __restrict__ a_s, float* __restrict__ a_d) {
    float* hs = (float*)smem;            // [64][INC] = 32 KB
    const int t = threadIdx.x;
    const int row0 = pb * 64;

    for (int q = t; q < 64 * 32; q += 256) {
        int rr = q >> 5;
        int c4 = (q & 31) << 2;
        int gr = row0 + rr;
        float4 v = (gr < NN) ? *reinterpret_cast<const float4*>(&h[(size_t)gr * INC + c4])
                             : make_float4(0.f, 0.f, 0.f, 0.f);
        *reinterpret_cast<float4*>(&hs[rr * INC + c4]) = v;
    }
    __syncthreads();

    const int j2 = t & 31;   // cols j2*4 .. j2*4+3
    const int rg = t >> 5;
    float acc[8][4];
#pragma unroll
    for (int r8 = 0; r8 < 8; r8++)
#pragma unroll
        for (int c = 0; c < 4; c++) acc[r8][c] = 0.f;

    float wA[4][4], wB[4][4];
    LOADW(wA, 0)
    for (int k = 0; k < INC; k += 8) {
        LOADW(wB, k + 4)
        FMAS(wA, k)
        if (k + 8 < INC) { LOADW(wA, k + 8) }
        FMAS(wB, k + 4)
    }

#pragma unroll
    for (int r8 = 0; r8 < 8; r8++) {
        int gr = row0 + rg * 8 + r8;
        if (gr < NN) {
            ushort4 sv;
            sv.x = f2h(acc[r8][0]);
            sv.y = f2h(acc[r8][1]);
            sv.z = f2h(acc[r8][2]);
            sv.w = f2h(acc[r8][3]);
            *reinterpret_cast<ushort4*>(&x_h[(size_t)gr * HC + j2 * 4]) = sv;
        }
    }

    // fused attention epilogue: lanes j2=0..15 hold head0 cols, 16..31 head1
    const int lane = t & 63;
    const int hidx = j2 >> 4;
    const float4 avs = *reinterpret_cast<const float4*>(&att_src[j2 * 4]);
    const float4 avd = *reinterpret_cast<const float4*>(&att_dst[j2 * 4]);
#pragma unroll
    for (int r8 = 0; r8 < 8; r8++) {
        float ps = acc[r8][0] * avs.x + acc[r8][1] * avs.y
                 + acc[r8][2] * avs.z + acc[r8][3] * avs.w;
        float pd = acc[r8][0] * avd.x + acc[r8][1] * avd.y
                 + acc[r8][2] * avd.z + acc[r8][3] * avd.w;
#pragma unroll
        for (int o = 1; o < 16; o <<= 1) {
            ps += __shfl_xor(ps, o);
            pd += __shfl_xor(pd, o);
        }
        int gr = row0 + rg * 8 + r8;
        if ((lane & 15) == 0 && gr < NN) {
            a_s[gr * 2 + hidx] = ps;
            a_d[gr * 2 + hidx] = pd;
        }
    }
}

// ---------------------------------------------------------------------------
// bin body (r9-proven): LDS counters + scan + LDS staging -> coalesced gbin.
// key (64-node ranges): (range10<<22) | ((dst&63)<<16) | src16
__device__ __forceinline__ void bin_body(
        char* smem, int b,
        const int* __restrict__ ei,
        unsigned int* __restrict__ gbin, unsigned short* __restrict__ bofs) {
    int* cnt = (int*)smem;                               // NR2
    int* ofs = cnt + NR2;                                // NR2+1
    int* cur = ofs + NR2 + 1;                            // NR2
    int* wsum = cur + NR2;                               // 4
    unsigned int* lbuf = (unsigned int*)(wsum + 4);      // EPB (16 KB) -> ~25.2 KB total
    const int t = threadIdx.x;

    for (int i = t; i < NR2; i += 256) cnt[i] = 0;
    __syncthreads();

    unsigned int pk[16];
    bool vd[16];
#pragma unroll
    for (int q = 0; q < 16; q++) {
        int i = b * EPB + q * 256 + t;
        vd[q] = (i < TOT);
        int s, d;
        if (i < EE)       { s = ei[i]; d = ei[EE + i]; }
        else if (i < TOT) { s = d = i - EE; }
        else              { s = d = 0; }
        pk[q] = ((unsigned int)(d >> 6) << 22) |
                ((unsigned int)(d & 63) << 16) | (unsigned int)s;
        if (vd[q]) atomicAdd(&cnt[pk[q] >> 22], 1);     // LDS atomic
    }
    __syncthreads();

    // exclusive scan cnt[0..NR2) -> ofs[0..NR2]; cur = copy (4 elems/thread)
    {
        int i0 = 4 * t;
        int v0 = (i0     < NR2) ? cnt[i0]     : 0;
        int v1 = (i0 + 1 < NR2) ? cnt[i0 + 1] : 0;
        int v2 = (i0 + 2 < NR2) ? cnt[i0 + 2] : 0;
        int v3 = (i0 + 3 < NR2) ? cnt[i0 + 3] : 0;
        int ps = v0 + v1 + v2 + v3;
        int sc = ps;
        int lane = t & 63, wid = t >> 6;
#pragma unroll
        for (int o = 1; o < 64; o <<= 1) {
            int u = __shfl_up(sc, o);
            if (lane >= o) sc += u;
        }
        if (lane == 63) wsum[wid] = sc;
        __syncthreads();
        int woff = 0;
        for (int ww = 0; ww < wid; ww++) woff += wsum[ww];
        int run = woff + sc - ps;
        if (i0     <= NR2) ofs[i0]     = run; if (i0     < NR2) cur[i0]     = run; run += v0;
        if (i0 + 1 <= NR2) ofs[i0 + 1] = run; if (i0 + 1 < NR2) cur[i0 + 1] = run; run += v1;
        if (i0 + 2 <= NR2) ofs[i0 + 2] = run; if (i0 + 2 < NR2) cur[i0 + 2] = run; run += v2;
        if (i0 + 3 <= NR2) ofs[i0 + 3] = run; if (i0 + 3 < NR2) cur[i0 + 3] = run;
    }
    __syncthreads();

#pragma unroll
    for (int q = 0; q < 16; q++) {
        if (vd[q]) {
            int pos = atomicAdd(&cur[pk[q] >> 22], 1);  // LDS atomic
            lbuf[pos] = pk[q];
        }
    }
    __syncthreads();

#pragma unroll
    for (int q = 0; q < 16; q++)
        gbin[(size_t)b * EPB + q * 256 + t] = lbuf[q * 256 + t];
    for (int i = t; i <= NR2; i += 256)
        bofs[(size_t)b * (NR2 + 1) + i] = (unsigned short)ofs[i];
}

// ---------------------------------------------------------------------------
// K1: fat kernel — blocks [0,NB1) bin, blocks [NB1,NB1+PROJB) proj+att.
__global__ __launch_bounds__(256) void gat_fused1(
        const float* __restrict__ h, const float* __restrict__ W,
        const float* __restrict__ att_src, const float* __restrict__ att_dst,
        const int* __restrict__ ei,
        unsigned int* __restrict__ gbin, unsigned short* __restrict__ bofs,
        unsigned short* __restrict__ x_h,
        float* __restrict__ a_s, float* __restrict__ a_d) {
    __shared__ __align__(16) char smem[64 * INC * 4];   // 32 KB union
    if (blockIdx.x < NB1)
        bin_body(smem, blockIdx.x, ei, gbin, bofs);
    else
        proj_body(smem, blockIdx.x - NB1, h, W, att_src, att_dst, x_h, a_s, a_d);
}

// ---------------------------------------------------------------------------
// K2: MERGED build+aggregate (r9-proven, byte-identical — session best).
// r10 (TLP), r11 (MFMA proj), r12 (ILP-8) all probed null/negative:
// phase-4's random 256B row-gather is at its fabric-throughput floor.
#define ACCUM(u32v, aL, aH)                                                   \
    asm("v_fma_mix_f32 %0, %1, %2, %0 op_sel_hi:[0,1,0]"                      \
        : "+v"(aL) : "v"(wk), "v"(u32v));                                     \
    asm("v_fma_mix_f32 %0, %1, %2, %0 op_sel:[0,1,0] op_sel_hi:[0,1,0]"       \
        : "+v"(aH) : "v"(wk), "v"(u32v));

__global__ __launch_bounds__(512) void gat_ragg(
        const unsigned int* __restrict__ gbin,
        const unsigned short* __restrict__ bofs,
        const uint4* __restrict__ x16,           // fp16 row = 16 x uint4
        const float2* __restrict__ a_s2, const float2* __restrict__ a_d2,
        const float4* __restrict__ bias4, float4* __restrict__ out4) {
    __shared__ int sbase[512];                 // segment-start scan (403 used)
    __shared__ int segofs[NB1];                // segment offset within its bin
    __shared__ unsigned short esrc[CAPR2];
    __shared__ unsigned char  edst[CAPR2];
    __shared__ unsigned int   pvh[CAPR2];      // fp16x2 p per edge
    __shared__ unsigned short csrc[PADC];      // ordered src per node-window
    __shared__ unsigned int   cpv[PADC];       // ordered fp16x2 p
    __shared__ int deg[RNG2];
    __shared__ int ofsP[RNG2];                 // padded window starts (+4/node)
    __shared__ int cur[RNG2];
    __shared__ int wsum[8];
    __shared__ int tot_sh;

    const int t = threadIdx.x;
    const int r = blockIdx.x;
    const int lane = t & 63, wid = t >> 6;

    if (t < RNG2) { deg[t] = 0; cur[t] = 0; }

    // phase 0: segment lengths (1/thread) -> 8-wave scan -> sbase, tot
    int c = 0;
    if (t < NB1) {
        int o0 = (int)bofs[(size_t)t * (NR2 + 1) + r];
        int o1 = (int)bofs[(size_t)t * (NR2 + 1) + r + 1];
        c = o1 - o0;
        segofs[t] = o0;
    }
    int sc = c;
#pragma unroll
    for (int o = 1; o < 64; o <<= 1) {
        int u = __shfl_up(sc, o);
        if (lane >= o) sc += u;
    }
    if (lane == 63) wsum[wid] = sc;
    __syncthreads();
    int woff = 0;
    for (int ww = 0; ww < wid; ww++) woff += wsum[ww];
    int excl = woff + sc - c;
    sbase[t] = excl;
    if (t == 511) tot_sh = excl + c;
    __syncthreads();
    const int tot = min(tot_sh, CAPR2);

    // phase 1: flat gather gbin -> LDS (binary search sbase), p compute,
    // degree count. All loads independent across e.
    const float2* __restrict__ adr = a_d2 + (size_t)r * RNG2;
    for (int e = t; e < tot; e += 512) {
        int lo = 0, hi = NB1 - 1;              // largest j with sbase[j] <= e
        while (lo < hi) {
            int mid = (lo + hi + 1) >> 1;
            if (sbase[mid] <= e) lo = mid; else hi = mid - 1;
        }
        unsigned int v = gbin[(size_t)lo * EPB + segofs[lo] + (e - sbase[lo])];
        int s  = (int)(v & 0xFFFFu);
        int dl = (int)((v >> 16) & 63u);
        esrc[e] = (unsigned short)s;
        edst[e] = (unsigned char)dl;
        float2 as = a_s2[s];
        float2 ad = adr[dl];                   // edge exists -> node valid
        float e0 = as.x + ad.x; e0 = (e0 > 0.f) ? e0 : NEG_SLOPE * e0;
        float e1 = as.y + ad.y; e1 = (e1 > 0.f) ? e1 : NEG_SLOPE * e1;
        pvh[e] = packp(__expf(e0), __expf(e1));
        atomicAdd(&deg[dl], 1);                // LDS atomic
    }
    __syncthreads();

    // phase 2: padded exclusive scan deg -> ofsP (wave 0 only; RNG2 == 64)
    if (t < RNG2) {
        int v = deg[t];
        int s2 = v;
#pragma unroll
        for (int o = 1; o < 64; o <<= 1) {
            int u = __shfl_up(s2, o);
            if (lane >= o) s2 += u;
        }
        ofsP[t] = (s2 - v) + 4 * t;            // +4 slack slots per node
    }
    __syncthreads();

    // phase 3: scatter (src, p) into node windows + zero the 4-pad
    for (int e = t; e < tot; e += 512) {
        int dl = edst[e];
        int slot = ofsP[dl] + atomicAdd(&cur[dl], 1);   // LDS atomic
        csrc[slot] = esrc[e];
        cpv[slot]  = pvh[e];
    }
    if (t < RNG2 * 4) {
        int j = t >> 2, q = t & 3;
        int slot = ofsP[j] + deg[j] + q;
        csrc[slot] = 0;
        cpv[slot] = 0;
    }
    __syncthreads();

    // phase 4: aggregate — wave w handles nodes w, w+8, ... (8 nodes/wave)
    const int sub = lane >> 4;           // edge index within 4-edge group
    const int cl  = lane & 15;           // channel oct
    const int hd  = cl >> 3;             // head
    const int hsh = hd << 4;             // shift to select head's half
    for (int jl = wid; jl < RNG2; jl += 8) {
        int n = r * RNG2 + jl;
        if (n >= NN) continue;
        const int dj = deg[jl];
        const int w0 = ofsP[jl];

        // denominators from stored p
        float d0 = 0.f, d1 = 0.f;
        for (int jj = lane; jj < dj; jj += 64) {
            unsigned int ph = cpv[w0 + jj];
            d0 += __half2float(__ushort_as_half((unsigned short)ph));
            d1 += __half2float(__ushort_as_half((unsigned short)(ph >> 16)));
        }
#pragma unroll
        for (int off = 32; off; off >>= 1) {
            d0 += __shfl_xor(d0, off);
            d1 += __shfl_xor(d1, off);
        }

        // channel loop (r6-proven): 4-edge groups, ILP-4
        float a0=0.f,a1=0.f,a2=0.f,a3=0.f,a4=0.f,a5=0.f,a6=0.f,a7=0.f;
        const int ng = (dj + 3) >> 2;
        int g = 0;
        for (; g + 4 <= ng; g += 4) {
#pragma unroll
            for (int k = 0; k < 4; k++) {
                int e = 4 * (g + k) + sub;
                int s = (int)csrc[w0 + e];
                unsigned int ph = cpv[w0 + e];
                float wk = __half2float(__ushort_as_half((unsigned short)(ph >> hsh)));
                uint4 u = x16[(size_t)s * 16 + cl];
                ACCUM(u.x, a0, a1)
                ACCUM(u.y, a2, a3)
                ACCUM(u.z, a4, a5)
                ACCUM(u.w, a6, a7)
            }
        }
        for (; g < ng; g++) {
            int e = 4 * g + sub;
            int s = (int)csrc[w0 + e];
            unsigned int ph = cpv[w0 + e];
            float wk = __half2float(__ushort_as_half((unsigned short)(ph >> hsh)));
            uint4 u = x16[(size_t)s * 16 + cl];
            ACCUM(u.x, a0, a1)
            ACCUM(u.y, a2, a3)
            ACCUM(u.z, a4, a5)
            ACCUM(u.w, a6, a7)
        }
#define MRG(a) a += __shfl_xor(a, 16); a += __shfl_xor(a, 32);
        MRG(a0) MRG(a1) MRG(a2) MRG(a3) MRG(a4) MRG(a5) MRG(a6) MRG(a7)
#undef MRG

        // epilogue spread over 32 lanes (r6-proven)
        if (lane < 32) {
            const int hf = lane >> 4;
            const float invd = 1.0f / (hd ? d1 : d0);
            float4 bb = bias4[cl * 2 + hf];
            float v0 = (hf ? a4 : a0) * invd + bb.x;
            float v1 = (hf ? a5 : a1) * invd + bb.y;
            float v2 = (hf ? a6 : a2) * invd + bb.z;
            float v3 = (hf ? a7 : a3) * invd + bb.w;
            v0 = (v0 > 0.f) ? v0 : __expf(v0) - 1.0f;
            v1 = (v1 > 0.f) ? v1 : __expf(v1) - 1.0f;
            v2 = (v2 > 0.f) ? v2 : __expf(v2) - 1.0f;
            v3 = (v3 > 0.f) ? v3 : __expf(v3) - 1.0f;
            out4[(size_t)n * 32 + cl * 2 + hf] = make_float4(v0, v1, v2, v3);
        }
    }
}

// ---------------------------------------------------------------------------
static inline size_t align256(size_t v) { return (v + 255) & ~(size_t)255; }

extern "C" void kernel_launch(void* const* d_in, const int* in_sizes, int n_in,
                              void* d_out, int out_size, void* d_ws, size_t ws_size,
                              hipStream_t stream) {
    const float* h_node  = (const float*)d_in[0];
    const int*   ei      = (const int*)d_in[1];
    const float* W       = (const float*)d_in[2];
    const float* att_src = (const float*)d_in[3];
    const float* att_dst = (const float*)d_in[4];
    const float* bias    = (const float*)d_in[5];
    float* out = (float*)d_out;

    // workspace layout (~21 MB)
    char* base = (char*)d_ws;
    size_t off = 0;
    unsigned short* x_h = (unsigned short*)(base + off);
    off = align256(off + (size_t)NN * HC * 2);
    float* a_s = (float*)(base + off);      off = align256(off + (size_t)NN * 2 * 4);
    float* a_d = (float*)(base + off);      off = align256(off + (size_t)NN * 2 * 4);
    unsigned int* gbin = (unsigned int*)(base + off);
    off = align256(off + (size_t)NB1 * EPB * 4);
    unsigned short* bofs = (unsigned short*)(base + off);
    off = align256(off + (size_t)NB1 * (NR2 + 1) * 2);
    (void)ws_size;

    gat_fused1<<<NB1 + PROJB, 256, 0, stream>>>(h_node, W, att_src, att_dst, ei,
                                                gbin, bofs, x_h, a_s, a_d);
    gat_ragg<<<NR2, 512, 0, stream>>>(gbin, bofs, (const uint4*)x_h,
                                      (const float2*)a_s, (const float2*)a_d,
                                      (const float4*)bias, (float4*)out);
}

// Round 14
// 178.468 us; speedup vs baseline: 1.1451x; 1.0461x over previous
//
#include <hip/hip_runtime.h>
#include <hip/hip_fp16.h>

// Problem constants (match reference.py)
#define NN 50000        // nodes
#define EE 1600000      // edges before self-loops
#define TOT (EE + NN)   // edges after self-loops
#define INC 128         // in channels
#define HC 128          // H*C out channels
#define NEG_SLOPE 0.2f

// binning (64-node ranges, r9-proven)
#define EPB 4096                        // edges per bin block
#define NB1 ((TOT + EPB - 1) / EPB)     // 403 bin blocks
#define RNG2 64                         // nodes per dst-range
#define NR2 ((NN + RNG2 - 1) / RNG2)    // 782 ranges
#define CAPR2 2624                      // edges/range cap (mean 2110, sigma 46; +11 sigma)
#define PADC (CAPR2 + 4 * RNG2)         // padded LDS-CSR capacity (4 slack/node)
#define PROJB ((NN + 63) / 64)          // 782 proj blocks

typedef __fp16 h8 __attribute__((ext_vector_type(8)));
typedef float f32x4v __attribute__((ext_vector_type(4)));

// fp16 store: x held as __half; aggr consumes it via v_fma_mix_f32.
__device__ __forceinline__ unsigned short f2h(float f) {
    __half h = __float2half(f);
    return __half_as_ushort(h);
}

// pack two f32 -> u32 of 2x f16 (builtin returns __fp16 vec2 — r8 lesson)
__device__ __forceinline__ unsigned int packp(float a, float b) {
    typedef __fp16 h2 __attribute__((ext_vector_type(2)));
    union { h2 h; unsigned int u; } cv;
    cv.h = __builtin_amdgcn_cvt_pkrtz(a, b);
    return cv.u;
}

// ---------------------------------------------------------------------------
// proj body, MFMA (r11 math — passed refcheck — with the staging bug fixed):
// r11 staged W^T with k varying fastest across lanes -> stride-512B scalar
// reads -> 16x line over-fetch (~820 MB L2 traffic) which ate the MFMA win.
// Fix: c varies fastest (coalesced float4 reads), same swizzled [c][k] LDS
// layout and identical read formula as r11.
//   A: row=lane&15, k=(lane>>4)*8+j   B: col=lane&15, same k
//   C/D: col=lane&15, row=(lane>>4)*4+reg
__device__ __forceinline__ void proj_body(
        char* smem, int pb,
        const float* __restrict__ h, const float* __restrict__ W,
        const float* __restrict__ att_src, const float* __restrict__ att_dst,
        unsigned short* __restrict__ x_h,
        float* __restrict__ a_s, float* __restrict__ a_d) {
    unsigned short* Wt = (unsigned short*)smem;   // [128 cols][128 k] fp16, swizzled
    const int t = threadIdx.x;
    const int w = t >> 6;
    const int lane = t & 63;
    const int l15 = lane & 15;
    const int lg  = lane >> 4;                    // 0..3
    const int row0 = pb * 64;

    // stage W^T fp16: COALESCED float4 global reads (c fastest), swizzled
    // u16 LDS writes. 4096 float4s over 256 threads = 16 iters.
    for (int idx = t; idx < (INC * HC) / 4; idx += 256) {
        int k  = idx >> 5;           // W row (0..127)
        int c4 = (idx & 31) << 2;    // col group base
        float4 wv = *reinterpret_cast<const float4*>(&W[(size_t)k * HC + c4]);
#pragma unroll
        for (int j = 0; j < 4; j++) {
            int c = c4 + j;
            float v = (j == 0) ? wv.x : (j == 1) ? wv.y : (j == 2) ? wv.z : wv.w;
            int byte = ((c * 128 + k) * 2) ^ ((c & 7) << 4);
            Wt[byte >> 1] = f2h(v);
        }
    }
    __syncthreads();

    // A fragments: wave w covers rows row0 + w*16 + (lane&15)
    const int arow = row0 + (w << 4) + l15;
    const bool av = arow < NN;
    const float* hrow = h + (size_t)arow * INC;
    h8 afr[4];
#pragma unroll
    for (int ks = 0; ks < 4; ks++) {
        int k0 = ks * 32 + (lg << 3);
        float4 f0 = av ? *reinterpret_cast<const float4*>(hrow + k0)
                       : make_float4(0.f, 0.f, 0.f, 0.f);
        float4 f1 = av ? *reinterpret_cast<const float4*>(hrow + k0 + 4)
                       : make_float4(0.f, 0.f, 0.f, 0.f);
        h8 a;
        a[0] = (__fp16)f0.x; a[1] = (__fp16)f0.y;
        a[2] = (__fp16)f0.z; a[3] = (__fp16)f0.w;
        a[4] = (__fp16)f1.x; a[5] = (__fp16)f1.y;
        a[6] = (__fp16)f1.z; a[7] = (__fp16)f1.w;
        afr[ks] = a;
    }

    // MFMA: acc[ct] = 16x16 tile (rows w*16.., cols ct*16..)
    f32x4v acc[8];
#pragma unroll
    for (int ct = 0; ct < 8; ct++) acc[ct] = (f32x4v){0.f, 0.f, 0.f, 0.f};
#pragma unroll
    for (int ks = 0; ks < 4; ks++) {
        int kk = ks * 32 + (lg << 3);
#pragma unroll
        for (int ct = 0; ct < 8; ct++) {
            int col = ct * 16 + l15;
            int byte = ((col * 128 + kk) * 2) ^ ((col & 7) << 4);
            h8 b = *reinterpret_cast<const h8*>(reinterpret_cast<const char*>(Wt) + byte);
            acc[ct] = __builtin_amdgcn_mfma_f32_16x16x32_f16(afr[ks], b, acc[ct], 0, 0, 0);
        }
    }

    // x_h store from C/D layout: lane's rows = w*16 + lg*4 + reg, col = ct*16+l15
#pragma unroll
    for (int reg = 0; reg < 4; reg++) {
        int grow = row0 + (w << 4) + (lg << 2) + reg;
        if (grow < NN) {
#pragma unroll
            for (int ct = 0; ct < 8; ct++)
                x_h[(size_t)grow * HC + ct * 16 + l15] = f2h(acc[ct][reg]);
        }
    }

    // attention epilogue: a_s/a_d per row, reduce over cols.
    // col = ct*16+l15; head0 = ct<4, head1 = ct>=4.
    float AS[8], AD[8];
#pragma unroll
    for (int ct = 0; ct < 8; ct++) {
        AS[ct] = att_src[ct * 16 + l15];
        AD[ct] = att_dst[ct * 16 + l15];
    }
#pragma unroll
    for (int reg = 0; reg < 4; reg++) {
        float ps0 = 0.f, ps1 = 0.f, pd0 = 0.f, pd1 = 0.f;
#pragma unroll
        for (int ct = 0; ct < 4; ct++) {
            ps0 += acc[ct][reg] * AS[ct];
            pd0 += acc[ct][reg] * AD[ct];
            ps1 += acc[ct + 4][reg] * AS[ct + 4];
            pd1 += acc[ct + 4][reg] * AD[ct + 4];
        }
#pragma unroll
        for (int o = 1; o < 16; o <<= 1) {
            ps0 += __shfl_xor(ps0, o);
            ps1 += __shfl_xor(ps1, o);
            pd0 += __shfl_xor(pd0, o);
            pd1 += __shfl_xor(pd1, o);
        }
        int grow = row0 + (w << 4) + (lg << 2) + reg;
        if (l15 == 0 && grow < NN) {
            a_s[grow * 2]     = ps0;
            a_s[grow * 2 + 1] = ps1;
            a_d[grow * 2]     = pd0;
            a_d[grow * 2 + 1] = pd1;
        }
    }
}

// ---------------------------------------------------------------------------
// bin body (r9-proven): LDS counters + scan + LDS staging -> coalesced gbin.
// key (64-node ranges): (range10<<22) | ((dst&63)<<16) | src16
__device__ __forceinline__ void bin_body(
        char* smem, int b,
        const int* __restrict__ ei,
        unsigned int* __restrict__ gbin, unsigned short* __restrict__ bofs) {
    int* cnt = (int*)smem;                               // NR2
    int* ofs = cnt + NR2;                                // NR2+1
    int* cur = ofs + NR2 + 1;                            // NR2
    int* wsum = cur + NR2;                               // 4
    unsigned int* lbuf = (unsigned int*)(wsum + 4);      // EPB (16 KB) -> ~25.2 KB total
    const int t = threadIdx.x;

    for (int i = t; i < NR2; i += 256) cnt[i] = 0;
    __syncthreads();

    unsigned int pk[16];
    bool vd[16];
#pragma unroll
    for (int q = 0; q < 16; q++) {
        int i = b * EPB + q * 256 + t;
        vd[q] = (i < TOT);
        int s, d;
        if (i < EE)       { s = ei[i]; d = ei[EE + i]; }
        else if (i < TOT) { s = d = i - EE; }
        else              { s = d = 0; }
        pk[q] = ((unsigned int)(d >> 6) << 22) |
                ((unsigned int)(d & 63) << 16) | (unsigned int)s;
        if (vd[q]) atomicAdd(&cnt[pk[q] >> 22], 1);     // LDS atomic
    }
    __syncthreads();

    // exclusive scan cnt[0..NR2) -> ofs[0..NR2]; cur = copy (4 elems/thread)
    {
        int i0 = 4 * t;
        int v0 = (i0     < NR2) ? cnt[i0]     : 0;
        int v1 = (i0 + 1 < NR2) ? cnt[i0 + 1] : 0;
        int v2 = (i0 + 2 < NR2) ? cnt[i0 + 2] : 0;
        int v3 = (i0 + 3 < NR2) ? cnt[i0 + 3] : 0;
        int ps = v0 + v1 + v2 + v3;
        int sc = ps;
        int lane = t & 63, wid = t >> 6;
#pragma unroll
        for (int o = 1; o < 64; o <<= 1) {
            int u = __shfl_up(sc, o);
            if (lane >= o) sc += u;
        }
        if (lane == 63) wsum[wid] = sc;
        __syncthreads();
        int woff = 0;
        for (int ww = 0; ww < wid; ww++) woff += wsum[ww];
        int run = woff + sc - ps;
        if (i0     <= NR2) ofs[i0]     = run; if (i0     < NR2) cur[i0]     = run; run += v0;
        if (i0 + 1 <= NR2) ofs[i0 + 1] = run; if (i0 + 1 < NR2) cur[i0 + 1] = run; run += v1;
        if (i0 + 2 <= NR2) ofs[i0 + 2] = run; if (i0 + 2 < NR2) cur[i0 + 2] = run; run += v2;
        if (i0 + 3 <= NR2) ofs[i0 + 3] = run; if (i0 + 3 < NR2) cur[i0 + 3] = run;
    }
    __syncthreads();

#pragma unroll
    for (int q = 0; q < 16; q++) {
        if (vd[q]) {
            int pos = atomicAdd(&cur[pk[q] >> 22], 1);  // LDS atomic
            lbuf[pos] = pk[q];
        }
    }
    __syncthreads();

#pragma unroll
    for (int q = 0; q < 16; q++)
        gbin[(size_t)b * EPB + q * 256 + t] = lbuf[q * 256 + t];
    for (int i = t; i <= NR2; i += 256)
        bofs[(size_t)b * (NR2 + 1) + i] = (unsigned short)ofs[i];
}

// ---------------------------------------------------------------------------
// K1: fat kernel — blocks [0,NB1) bin, blocks [NB1,NB1+PROJB) proj+att.
__global__ __launch_bounds__(256) void gat_fused1(
        const float* __restrict__ h, const float* __restrict__ W,
        const float* __restrict__ att_src, const float* __restrict__ att_dst,
        const int* __restrict__ ei,
        unsigned int* __restrict__ gbin, unsigned short* __restrict__ bofs,
        unsigned short* __restrict__ x_h,
        float* __restrict__ a_s, float* __restrict__ a_d) {
    __shared__ __align__(16) char smem[INC * HC * 2];   // 32 KB union (Wt / bin)
    if (blockIdx.x < NB1)
        bin_body(smem, blockIdx.x, ei, gbin, bofs);
    else
        proj_body(smem, blockIdx.x - NB1, h, W, att_src, att_dst, x_h, a_s, a_d);
}

// ---------------------------------------------------------------------------
// K2: MERGED build+aggregate (r9-proven, byte-identical — session best).
// r10 (TLP), r11 (MFMA proj), r12 (ILP-8) all probed null/negative on ragg:
// phase-4's random 256B row-gather is at its fabric-throughput floor.
#define ACCUM(u32v, aL, aH)                                                   \
    asm("v_fma_mix_f32 %0, %1, %2, %0 op_sel_hi:[0,1,0]"                      \
        : "+v"(aL) : "v"(wk), "v"(u32v));                                     \
    asm("v_fma_mix_f32 %0, %1, %2, %0 op_sel:[0,1,0] op_sel_hi:[0,1,0]"       \
        : "+v"(aH) : "v"(wk), "v"(u32v));

__global__ __launch_bounds__(512) void gat_ragg(
        const unsigned int* __restrict__ gbin,
        const unsigned short* __restrict__ bofs,
        const uint4* __restrict__ x16,           // fp16 row = 16 x uint4
        const float2* __restrict__ a_s2, const float2* __restrict__ a_d2,
        const float4* __restrict__ bias4, float4* __restrict__ out4) {
    __shared__ int sbase[512];                 // segment-start scan (403 used)
    __shared__ int segofs[NB1];                // segment offset within its bin
    __shared__ unsigned short esrc[CAPR2];
    __shared__ unsigned char  edst[CAPR2];
    __shared__ unsigned int   pvh[CAPR2];      // fp16x2 p per edge
    __shared__ unsigned short csrc[PADC];      // ordered src per node-window
    __shared__ unsigned int   cpv[PADC];       // ordered fp16x2 p
    __shared__ int deg[RNG2];
    __shared__ int ofsP[RNG2];                 // padded window starts (+4/node)
    __shared__ int cur[RNG2];
    __shared__ int wsum[8];
    __shared__ int tot_sh;

    const int t = threadIdx.x;
    const int r = blockIdx.x;
    const int lane = t & 63, wid = t >> 6;

    if (t < RNG2) { deg[t] = 0; cur[t] = 0; }

    // phase 0: segment lengths (1/thread) -> 8-wave scan -> sbase, tot
    int c = 0;
    if (t < NB1) {
        int o0 = (int)bofs[(size_t)t * (NR2 + 1) + r];
        int o1 = (int)bofs[(size_t)t * (NR2 + 1) + r + 1];
        c = o1 - o0;
        segofs[t] = o0;
    }
    int sc = c;
#pragma unroll
    for (int o = 1; o < 64; o <<= 1) {
        int u = __shfl_up(sc, o);
        if (lane >= o) sc += u;
    }
    if (lane == 63) wsum[wid] = sc;
    __syncthreads();
    int woff = 0;
    for (int ww = 0; ww < wid; ww++) woff += wsum[ww];
    int excl = woff + sc - c;
    sbase[t] = excl;
    if (t == 511) tot_sh = excl + c;
    __syncthreads();
    const int tot = min(tot_sh, CAPR2);

    // phase 1: flat gather gbin -> LDS (binary search sbase), p compute,
    // degree count. All loads independent across e.
    const float2* __restrict__ adr = a_d2 + (size_t)r * RNG2;
    for (int e = t; e < tot; e += 512) {
        int lo = 0, hi = NB1 - 1;              // largest j with sbase[j] <= e
        while (lo < hi) {
            int mid = (lo + hi + 1) >> 1;
            if (sbase[mid] <= e) lo = mid; else hi = mid - 1;
        }
        unsigned int v = gbin[(size_t)lo * EPB + segofs[lo] + (e - sbase[lo])];
        int s  = (int)(v & 0xFFFFu);
        int dl = (int)((v >> 16) & 63u);
        esrc[e] = (unsigned short)s;
        edst[e] = (unsigned char)dl;
        float2 as = a_s2[s];
        float2 ad = adr[dl];                   // edge exists -> node valid
        float e0 = as.x + ad.x; e0 = (e0 > 0.f) ? e0 : NEG_SLOPE * e0;
        float e1 = as.y + ad.y; e1 = (e1 > 0.f) ? e1 : NEG_SLOPE * e1;
        pvh[e] = packp(__expf(e0), __expf(e1));
        atomicAdd(&deg[dl], 1);                // LDS atomic
    }
    __syncthreads();

    // phase 2: padded exclusive scan deg -> ofsP (wave 0 only; RNG2 == 64)
    if (t < RNG2) {
        int v = deg[t];
        int s2 = v;
#pragma unroll
        for (int o = 1; o < 64; o <<= 1) {
            int u = __shfl_up(s2, o);
            if (lane >= o) s2 += u;
        }
        ofsP[t] = (s2 - v) + 4 * t;            // +4 slack slots per node
    }
    __syncthreads();

    // phase 3: scatter (src, p) into node windows + zero the 4-pad
    for (int e = t; e < tot; e += 512) {
        int dl = edst[e];
        int slot = ofsP[dl] + atomicAdd(&cur[dl], 1);   // LDS atomic
        csrc[slot] = esrc[e];
        cpv[slot]  = pvh[e];
    }
    if (t < RNG2 * 4) {
        int j = t >> 2, q = t & 3;
        int slot = ofsP[j] + deg[j] + q;
        csrc[slot] = 0;
        cpv[slot] = 0;
    }
    __syncthreads();

    // phase 4: aggregate — wave w handles nodes w, w+8, ... (8 nodes/wave)
    const int sub = lane >> 4;           // edge index within 4-edge group
    const int cl  = lane & 15;           // channel oct
    const int hd  = cl >> 3;             // head
    const int hsh = hd << 4;             // shift to select head's half
    for (int jl = wid; jl < RNG2; jl += 8) {
        int n = r * RNG2 + jl;
        if (n >= NN) continue;
        const int dj = deg[jl];
        const int w0 = ofsP[jl];

        // denominators from stored p
        float d0 = 0.f, d1 = 0.f;
        for (int jj = lane; jj < dj; jj += 64) {
            unsigned int ph = cpv[w0 + jj];
            d0 += __half2float(__ushort_as_half((unsigned short)ph));
            d1 += __half2float(__ushort_as_half((unsigned short)(ph >> 16)));
        }
#pragma unroll
        for (int off = 32; off; off >>= 1) {
            d0 += __shfl_xor(d0, off);
            d1 += __shfl_xor(d1, off);
        }

        // channel loop (r6-proven): 4-edge groups, ILP-4
        float a0=0.f,a1=0.f,a2=0.f,a3=0.f,a4=0.f,a5=0.f,a6=0.f,a7=0.f;
        const int ng = (dj + 3) >> 2;
        int g = 0;
        for (; g + 4 <= ng; g += 4) {
#pragma unroll
            for (int k = 0; k < 4; k++) {
                int e = 4 * (g + k) + sub;
                int s = (int)csrc[w0 + e];
                unsigned int ph = cpv[w0 + e];
                float wk = __half2float(__ushort_as_half((unsigned short)(ph >> hsh)));
                uint4 u = x16[(size_t)s * 16 + cl];
                ACCUM(u.x, a0, a1)
                ACCUM(u.y, a2, a3)
                ACCUM(u.z, a4, a5)
                ACCUM(u.w, a6, a7)
            }
        }
        for (; g < ng; g++) {
            int e = 4 * g + sub;
            int s = (int)csrc[w0 + e];
            unsigned int ph = cpv[w0 + e];
            float wk = __half2float(__ushort_as_half((unsigned short)(ph >> hsh)));
            uint4 u = x16[(size_t)s * 16 + cl];
            ACCUM(u.x, a0, a1)
            ACCUM(u.y, a2, a3)
            ACCUM(u.z, a4, a5)
            ACCUM(u.w, a6, a7)
        }
#define MRG(a) a += __shfl_xor(a, 16); a += __shfl_xor(a, 32);
        MRG(a0) MRG(a1) MRG(a2) MRG(a3) MRG(a4) MRG(a5) MRG(a6) MRG(a7)
#undef MRG

        // epilogue spread over 32 lanes (r6-proven)
        if (lane < 32) {
            const int hf = lane >> 4;
            const float invd = 1.0f / (hd ? d1 : d0);
            float4 bb = bias4[cl * 2 + hf];
            float v0 = (hf ? a4 : a0) * invd + bb.x;
            float v1 = (hf ? a5 : a1) * invd + bb.y;
            float v2 = (hf ? a6 : a2) * invd + bb.z;
            float v3 = (hf ? a7 : a3) * invd + bb.w;
            v0 = (v0 > 0.f) ? v0 : __expf(v0) - 1.0f;
            v1 = (v1 > 0.f) ? v1 : __expf(v1) - 1.0f;
            v2 = (v2 > 0.f) ? v2 : __expf(v2) - 1.0f;
            v3 = (v3 > 0.f) ? v3 : __expf(v3) - 1.0f;
            out4[(size_t)n * 32 + cl * 2 + hf] = make_float4(v0, v1, v2, v3);
        }
    }
}

// ---------------------------------------------------------------------------
static inline size_t align256(size_t v) { return (v + 255) & ~(size_t)255; }

extern "C" void kernel_launch(void* const* d_in, const int* in_sizes, int n_in,
                              void* d_out, int out_size, void* d_ws, size_t ws_size,
                              hipStream_t stream) {
    const float* h_node  = (const float*)d_in[0];
    const int*   ei      = (const int*)d_in[1];
    const float* W       = (const float*)d_in[2];
    const float* att_src = (const float*)d_in[3];
    const float* att_dst = (const float*)d_in[4];
    const float* bias    = (const float*)d_in[5];
    float* out = (float*)d_out;

    // workspace layout (~21 MB)
    char* base = (char*)d_ws;
    size_t off = 0;
    unsigned short* x_h = (unsigned short*)(base + off);
    off = align256(off + (size_t)NN * HC * 2);
    float* a_s = (float*)(base + off);      off = align256(off + (size_t)NN * 2 * 4);
    float* a_d = (float*)(base + off);      off = align256(off + (size_t)NN * 2 * 4);
    unsigned int* gbin = (unsigned int*)(base + off);
    off = align256(off + (size_t)NB1 * EPB * 4);
    unsigned short* bofs = (unsigned short*)(base + off);
    off = align256(off + (size_t)NB1 * (NR2 + 1) * 2);
    (void)ws_size;

    gat_fused1<<<NB1 + PROJB, 256, 0, stream>>>(h_node, W, att_src, att_dst, ei,
                                                gbin, bofs, x_h, a_s, a_d);
    gat_ragg<<<NR2, 512, 0, stream>>>(gbin, bofs, (const uint4*)x_h,
                                      (const float2*)a_s, (const float2*)a_d,
                                      (const float4*)bias, (float4*)out);
}